// Round 7
// baseline (47.978 us; speedup 1.0000x reference)
//
#include <hip/hip_runtime.h>

// eTofts model: B=8, T=60, H=W=256.
//   params[B,3,H,W], Cp[B,T], S0[B,1,H,W], T1[B,1,H,W] -> St[B,T,H,W] fp32
// True HBM traffic: 125.8 MB out + ~10.5 MB in => ~19 us floor at 7 TB/s.
//
// R6 lesson: store burst regressed -> queue depth excluded. All 1-generation
// configs (512-2048 blocks fully resident) pin at ~33 us. The fill kernel
// (7 TB/s) differs structurally in ONE remaining way: ~3 waves/CU with ~10
// pipelined block generations (few write streams; drain of gen n overlaps
// compute of gen n+1). This round replicates that: 15 chunks x 4 frames ->
// 1920 blocks, 60 KB dynamic-LDS pad caps residency at 2 blocks/CU (8 waves),
// ~3.75 generations. nt stores interleaved per frame (R4's best pattern).

#define N_TIME 60
#define HW (256 * 256)
#define FPC 4                          // frames per chunk
#define CHUNKS (N_TIME / FPC)          // 15
#define PXB 4096                       // pixels per block (256 thr * 16 px)
#define LDS_PAD 61440                  // 60 KB -> 2 blocks/CU (160 KB LDS/CU)

typedef float f32x4 __attribute__((ext_vector_type(4)));

__global__ __launch_bounds__(256, 2) void etofts_kernel(
    const float* __restrict__ params,  // [B,3,H,W]
    const float* __restrict__ Cp,      // [B,T]
    const float* __restrict__ S0,      // [B,1,H,W]
    const float* __restrict__ T1,      // [B,1,H,W]
    float* __restrict__ out)           // [B,T,H,W]
{
    const float DT     = 5.0f;
    const float TR     = 5.0f;
    const float EPS    = 1e-8f;
    const float COS_FA = 0.9848077530122081f;            // cos(10 deg)
    const float QC2    = 0.0225f * 1.4426950408889634f;  // (R1*TR/1000)*log2(e)

    // 1920 blocks = 8 b * 15 chunks * 16 tiles. All block-uniform splits.
    const int bx    = blockIdx.x;
    const int b     = bx / 240;          // scalar magic-mul
    const int rem   = bx - b * 240;
    const int chunk = rem >> 4;          // 0..14
    const int tile  = rem & 15;

    // Wave w owns a 4 KB contiguous span per frame.
    const int w    = threadIdx.x >> 6;
    const int lane = threadIdx.x & 63;
    const int pixw = tile * PXB + w * 1024 + lane * 4;

    const float* p0 = params + ((size_t)b * 3 + 0) * HW + pixw;
    const float* p1 = params + ((size_t)b * 3 + 1) * HW + pixw;
    const float* p2 = params + ((size_t)b * 3 + 2) * HW + pixw;
    const float* ps = S0 + (size_t)b * HW + pixw;
    const float* pt = T1 + (size_t)b * HW + pixw;

    float Kt[16], vp[16], decay[16], Ce[16], eP[16], Kc[16], d0[16], d1[16];

#pragma unroll
    for (int q = 0; q < 4; ++q) {
        const float4 kt4 = *reinterpret_cast<const float4*>(p0 + q * 256);
        const float4 vp4 = *reinterpret_cast<const float4*>(p1 + q * 256);
        const float4 ve4 = *reinterpret_cast<const float4*>(p2 + q * 256);
        const float4 s04 = *reinterpret_cast<const float4*>(ps + q * 256);
        const float4 t14 = *reinterpret_cast<const float4*>(pt + q * 256);
        const float ktv[4] = {kt4.x, kt4.y, kt4.z, kt4.w};
        const float vpv[4] = {vp4.x, vp4.y, vp4.z, vp4.w};
        const float vev[4] = {ve4.x, ve4.y, ve4.z, ve4.w};
        const float s0v[4] = {s04.x, s04.y, s04.z, s04.w};
        const float t1v[4] = {t14.x, t14.y, t14.z, t14.w};
#pragma unroll
        for (int i = 0; i < 4; ++i) {
            const int j = q * 4 + i;
            const float Ktrans = ktv[i] * (1.0f / 60.0f);
            const float Kep    = __fdividef(Ktrans, vev[i] + EPS);
            Kt[j]    = Ktrans;
            vp[j]    = vpv[i];
            decay[j] = __expf(-Kep * DT);
            const float P = __fdividef(TR, t1v[i] + EPS);
            const float e = __expf(-P);
            eP[j] = e;
            Kc[j] = (1.0f - COS_FA * e) * s0v[i];
            const float den1 = 1.0f - e;
            d0[j] = den1 + EPS;              // den = d0 - d1*ePQ
            d1[j] = COS_FA * den1;
            Ce[j] = 0.0f;
        }
    }

    const float* cp_row = Cp + b * N_TIME;   // uniform -> s_load
    const int t0 = chunk * FPC;

    // Replay the fma-only recurrence up to this chunk's start (<=56 iters).
    for (int t = 0; t < t0; ++t) {
        const float cpdt = cp_row[t] * DT;
#pragma unroll
        for (int j = 0; j < 16; ++j) Ce[j] = Ce[j] * decay[j] + cpdt;
    }

    float* outp = out + ((size_t)(b * N_TIME + t0)) * HW + pixw;

#pragma unroll
    for (int k = 0; k < FPC; ++k) {
        const float cp   = cp_row[t0 + k];
        const float cpdt = cp * DT;
        float* op = outp + (size_t)k * HW;
#pragma unroll
        for (int q = 0; q < 4; ++q) {
            float st[4];
#pragma unroll
            for (int i = 0; i < 4; ++i) {
                const int j = q * 4 + i;
                Ce[j] = Ce[j] * decay[j] + cpdt;
                const float Ct  = vp[j] * cp + Kt[j] * Ce[j];
                const float ePQ = eP[j] * exp2f(-QC2 * Ct);
                const float num = Kc[j] - Kc[j] * ePQ;
                const float den = d0[j] - d1[j] * ePQ;
                st[i] = __fdividef(num, den);
            }
            f32x4 v = {st[0], st[1], st[2], st[3]};
            __builtin_nontemporal_store(v, reinterpret_cast<f32x4*>(op + q * 256));
        }
    }
}

extern "C" void kernel_launch(void* const* d_in, const int* in_sizes, int n_in,
                              void* d_out, int out_size, void* d_ws, size_t ws_size,
                              hipStream_t stream) {
    const float* params = (const float*)d_in[0];
    const float* Cp     = (const float*)d_in[1];
    const float* S0     = (const float*)d_in[2];
    const float* T1     = (const float*)d_in[3];
    float* out          = (float*)d_out;

    const int grid = 8 * CHUNKS * (HW / PXB);  // 1920 blocks
    // 60 KB dynamic LDS (never referenced): caps residency at 2 blocks/CU so
    // block generations pipeline like the 7 TB/s fill kernel (~3.75 gens).
    etofts_kernel<<<grid, 256, LDS_PAD, stream>>>(params, Cp, S0, T1, out);
}

// Round 8
// 38.064 us; speedup vs baseline: 1.2605x; 1.2605x over previous
//
#include <hip/hip_runtime.h>

// eTofts model: B=8, T=60, H=W=256.
//   params[B,3,H,W], Cp[B,T], S0[B,1,H,W], T1[B,1,H,W] -> St[B,T,H,W] fp32
// True HBM traffic: 125.8 MB out + 10.5 MB in => ~19.5 us floor at 7 TB/s.
//
// R7 lesson: LDS-pad generations regressed (48us) - confounded by 15x input
// re-read + replay + thin occupancy. R8 isolates generation overlap cleanly:
// CHUNKS=1 (inputs read ONCE, no replay; thread owns all 60 frames of 1 px),
// 512 blocks (8 waves/CU, R4-proven), 4 sequential tiles per block with
// next-tile input prefetch issued before the current frame loop. Gen n+1
// reads+constants overlap gen n store drain; endpgm tail = 1/4 of work.

#define N_TIME 60
#define HW 65536
#define GENS 4
#define GRID 512
#define TPB 256
// tile = 256 px (one per thread); 2048 tiles; block bx does tiles bx+g*GRID.

struct In5 { float kt, vp, ve, s0, t1; };

__device__ __forceinline__ In5 load_tile(const float* __restrict__ params,
                                         const float* __restrict__ S0,
                                         const float* __restrict__ T1,
                                         int tile, int tid) {
    const int p   = tile * 256 + tid;   // global pixel 0..524287
    const int b   = p >> 16;
    const int off = p & 65535;
    const float* pb = params + (size_t)b * 3 * HW + off;
    In5 r;
    r.kt = pb[0];
    r.vp = pb[HW];
    r.ve = pb[2 * HW];
    r.s0 = S0[(size_t)b * HW + off];
    r.t1 = T1[(size_t)b * HW + off];
    return r;
}

__global__ __launch_bounds__(TPB) void etofts_kernel(
    const float* __restrict__ params,
    const float* __restrict__ Cp,
    const float* __restrict__ S0,
    const float* __restrict__ T1,
    float* __restrict__ out)
{
    const float DT     = 5.0f;
    const float TR     = 5.0f;
    const float EPS    = 1e-8f;
    const float COS_FA = 0.9848077530122081f;            // cos(10 deg)
    const float QC2    = 0.0225f * 1.4426950408889634f;  // (R1*TR/1000)*log2(e)

    const int bx  = blockIdx.x;
    const int tid = threadIdx.x;

    In5 cur = load_tile(params, S0, T1, bx, tid);

#pragma unroll
    for (int g = 0; g < GENS; ++g) {
        const int tile = bx + g * GRID;

        // Prefetch next generation's inputs; loads stay in flight across the
        // frame loop (first use is after it), overlapping this gen's stores.
        In5 nxt;
        if (g + 1 < GENS) nxt = load_tile(params, S0, T1, bx + (g + 1) * GRID, tid);

        const int b   = tile >> 8;                 // block-uniform -> s_load Cp
        const int off = (tile & 255) * 256 + tid;

        const float Ktrans = cur.kt * (1.0f / 60.0f);
        const float Kep    = __fdividef(Ktrans, cur.ve + EPS);
        const float dec    = __expf(-Kep * DT);
        const float P      = __fdividef(TR, cur.t1 + EPS);
        const float e      = __expf(-P);
        const float Kc     = (1.0f - COS_FA * e) * cur.s0;
        const float den1   = 1.0f - e;
        const float d0     = den1 + EPS;           // den = d0 - d1*ePQ
        const float d1     = COS_FA * den1;
        const float vpv    = cur.vp;
        float Ce = 0.0f;

        const float* cp_row = Cp + b * N_TIME;     // uniform -> scalar loads
        float* op = out + ((size_t)b * N_TIME) * HW + off;

#pragma unroll 4
        for (int t = 0; t < N_TIME; ++t) {
            const float cp = cp_row[t];
            Ce = Ce * dec + cp * DT;
            const float Ct  = vpv * cp + Ktrans * Ce;
            const float ePQ = e * exp2f(-QC2 * Ct);
            const float num = Kc - Kc * ePQ;
            const float den = d0 - d1 * ePQ;
            __builtin_nontemporal_store(__fdividef(num, den), op + (size_t)t * HW);
        }

        if (g + 1 < GENS) cur = nxt;
    }
}

extern "C" void kernel_launch(void* const* d_in, const int* in_sizes, int n_in,
                              void* d_out, int out_size, void* d_ws, size_t ws_size,
                              hipStream_t stream) {
    const float* params = (const float*)d_in[0];
    const float* Cp     = (const float*)d_in[1];
    const float* S0     = (const float*)d_in[2];
    const float* T1     = (const float*)d_in[3];
    float* out          = (float*)d_out;

    etofts_kernel<<<GRID, TPB, 0, stream>>>(params, Cp, S0, T1, out);
}